// Round 14
// baseline (159.431 us; speedup 1.0000x reference)
//
#include <hip/hip_runtime.h>
#include <hip/hip_bf16.h>
#include <hip/hip_cooperative_groups.h>

namespace cg = cooperative_groups;

#define NROWS 4096
#define TWO_N 8192
#define DDIM 64
#define INV_T 20.0f
// exp(dot*INV_T) = 2^(dot*INV_T*log2e); fold sqrt of the scale into each operand
#define SCALE2 5.3716292f   // sqrt(20 * 1.4426950408889634)
#define NPANEL 64           // 8192 / 128

typedef short bf16x8 __attribute__((ext_vector_type(8)));
typedef float f32x4 __attribute__((ext_vector_type(4)));

__device__ __forceinline__ unsigned short f32_to_bf16_rne(float f) {
    unsigned int u = __float_as_uint(f);
    return (unsigned short)((u + 0x7fffu + ((u >> 16) & 1u)) >> 16);
}

__device__ __forceinline__ float fast_exp2(float x) {
    float r;
    asm("v_exp_f32 %0, %1" : "=v"(r) : "v"(x));
    return r;
}

// featsT fragment-major layout: element (row=16g+lr, col=kb*32+lk*8+e) at
//   featsT[g*1024 + kb*512 + (lk*16+lr)*8 + e]
// -> an MFMA fragment load is featsT + g*1024 + kb*512 + lane*8 (1KB coalesced).
//
// NgP[k][i]: for row i in panel p, slot k is written by exactly one tile-block:
// rows of (p,k) for k>=p, cols of (k,p) for k<p  ->  Ng[i] = sum_k NgP[k][i].

__global__ __launch_bounds__(512) void fused_kernel(const float* __restrict__ f1,
                                                    const float* __restrict__ f2,
                                                    const int* __restrict__ label,
                                                    unsigned short* __restrict__ featsT,
                                                    float* __restrict__ posdot,
                                                    float* __restrict__ NgP,
                                                    int* __restrict__ cntG,
                                                    float* __restrict__ out) {
    cg::grid_group grid = cg::this_grid();
    const int tid = threadIdx.x;
    const int bid = blockIdx.x;
    const int G = gridDim.x;

    __shared__ float rowP[2][128];
    __shared__ float colP[4][128];
    __shared__ int cnt[16];
    __shared__ float red[8];

    // ================= Phase A: prep (+histogram, +zero out) =================
    if (bid == 0 && tid == 0) out[0] = 0.f;
    for (int t = bid * 512 + tid; t < NROWS * 16; t += G * 512) {
        int r = t >> 4;
        int q = t & 15;
        int j = r * DDIM + q * 4;
        float4 a = *reinterpret_cast<const float4*>(&f1[j]);
        float4 b = *reinterpret_cast<const float4*>(&f2[j]);
        float d = a.x * b.x + a.y * b.y + a.z * b.z + a.w * b.w;
        d += __shfl_xor(d, 1);
        d += __shfl_xor(d, 2);
        d += __shfl_xor(d, 4);
        d += __shfl_xor(d, 8);
        if (q == 0) posdot[r] = d * INV_T;
        ushort4 ua = make_ushort4(f32_to_bf16_rne(a.x * SCALE2), f32_to_bf16_rne(a.y * SCALE2),
                                  f32_to_bf16_rne(a.z * SCALE2), f32_to_bf16_rne(a.w * SCALE2));
        ushort4 ub = make_ushort4(f32_to_bf16_rne(b.x * SCALE2), f32_to_bf16_rne(b.y * SCALE2),
                                  f32_to_bf16_rne(b.z * SCALE2), f32_to_bf16_rne(b.w * SCALE2));
        int g1 = r >> 4;
        int lr2 = r & 15;
        int kb = q >> 3;
        int lk2 = (q & 7) >> 1;
        int e  = (q & 1) * 4;
        int off = g1 * 1024 + kb * 512 + (lk2 * 16 + lr2) * 8 + e;
        *reinterpret_cast<ushort4*>(&featsT[off]) = ua;                 // f1: groups 0..255
        *reinterpret_cast<ushort4*>(&featsT[off + 256 * 1024]) = ub;    // f2: groups 256..511
    }
    if (bid == 0) {
        if (tid < 16) cnt[tid] = 0;
        __syncthreads();
        for (int i = tid; i < NROWS; i += 512) atomicAdd(&cnt[label[i]], 1);
        __syncthreads();
        if (tid < 16) cntG[tid] = cnt[tid];
    }
    grid.sync();

    // ================= Phase B: upper-triangle 128x128 tiles =================
    const int wid = tid >> 6;
    const int lane = tid & 63;
    const int lr = lane & 15;
    const int lk = lane >> 4;
    const int wm = wid >> 1;         // 0..3
    const int wn = wid & 1;          // 0..1

    for (int tile = bid; tile < NPANEL * NPANEL; tile += G) {
        const int pr = tile >> 6;
        const int pc = tile & 63;
        if (pc < pr) continue;
        const int rowBase = pr * 128 + wm * 32;
        const int colBase = pc * 128 + wn * 64;
        const int gr0 = rowBase >> 4;
        const int gc0 = colBase >> 4;

        f32x4 acc[2][4];
        f32x4 zero = {0.f, 0.f, 0.f, 0.f};
        #pragma unroll
        for (int m = 0; m < 2; ++m)
            #pragma unroll
            for (int n = 0; n < 4; ++n) acc[m][n] = zero;

        #pragma unroll
        for (int kb = 0; kb < 2; ++kb) {
            bf16x8 afr[2], bfr[4];
            #pragma unroll
            for (int m = 0; m < 2; ++m)
                afr[m] = *reinterpret_cast<const bf16x8*>(
                    &featsT[(gr0 + m) * 1024 + kb * 512 + lane * 8]);
            #pragma unroll
            for (int n = 0; n < 4; ++n)
                bfr[n] = *reinterpret_cast<const bf16x8*>(
                    &featsT[(gc0 + n) * 1024 + kb * 512 + lane * 8]);
            #pragma unroll
            for (int m = 0; m < 2; ++m)
                #pragma unroll
                for (int n = 0; n < 4; ++n)
                    acc[m][n] = __builtin_amdgcn_mfma_f32_16x16x32_bf16(afr[m], bfr[n], acc[m][n], 0, 0, 0);
        }

        int rl[2][4];
        #pragma unroll
        for (int m = 0; m < 2; ++m)
            #pragma unroll
            for (int r = 0; r < 4; ++r)
                rl[m][r] = label[(rowBase + m * 16 + lk * 4 + r) & (NROWS - 1)];
        int cl[4];
        #pragma unroll
        for (int n = 0; n < 4; ++n)
            cl[n] = label[(colBase + n * 16 + lr) & (NROWS - 1)];

        float rsum[2][4];
        float csum[4] = {0.f, 0.f, 0.f, 0.f};
        #pragma unroll
        for (int m = 0; m < 2; ++m)
            #pragma unroll
            for (int r = 0; r < 4; ++r) {
                int lab = rl[m][r];
                float s = 0.f;
                #pragma unroll
                for (int n = 0; n < 4; ++n) {
                    float e = fast_exp2(acc[m][n][r]);   // = exp(dot/T)
                    float me = (cl[n] != lab) ? e : 0.f;
                    s += me;
                    csum[n] += me;
                }
                rsum[m][r] = s;
            }

        #pragma unroll
        for (int m = 0; m < 2; ++m)
            #pragma unroll
            for (int r = 0; r < 4; ++r) {
                float v = rsum[m][r];
                v += __shfl_xor(v, 1);
                v += __shfl_xor(v, 2);
                v += __shfl_xor(v, 4);
                v += __shfl_xor(v, 8);
                if (lr == 0) rowP[wn][wm * 32 + m * 16 + lk * 4 + r] = v;
            }
        #pragma unroll
        for (int n = 0; n < 4; ++n) {
            float v = csum[n];
            v += __shfl_xor(v, 16);
            v += __shfl_xor(v, 32);
            if (lane < 16) colP[wm][wn * 64 + n * 16 + lr] = v;
        }
        __syncthreads();

        if (tid < 128) {
            NgP[pc * TWO_N + pr * 128 + tid] = rowP[0][tid] + rowP[1][tid];
        } else if (tid < 256 && pr < pc) {
            int c = tid - 128;
            NgP[pr * TWO_N + pc * 128 + c] = colP[0][c] + colP[1][c] + colP[2][c] + colP[3][c];
        }
        __syncthreads();
    }
    grid.sync();

    // ================= Phase C: final loss =================
    if (bid < TWO_N / 512) {
        int i = bid * 512 + tid;
        float a0 = 0.f, a1 = 0.f, a2 = 0.f, a3 = 0.f;
        #pragma unroll
        for (int k = 0; k < NPANEL; k += 4) {
            a0 += NgP[(k + 0) * TWO_N + i];
            a1 += NgP[(k + 1) * TWO_N + i];
            a2 += NgP[(k + 2) * TWO_N + i];
            a3 += NgP[(k + 3) * TWO_N + i];
        }
        float ng = (a0 + a1) + (a2 + a3);
        int base = i & (NROWS - 1);
        float pd = posdot[base];
        float gs = 2.0f * (float)cntG[label[base]];
        float s = (__logf(ng + __expf(pd)) - pd) / gs;

        #pragma unroll
        for (int m = 32; m; m >>= 1) s += __shfl_xor(s, m);
        if ((tid & 63) == 0) red[tid >> 6] = s;
        __syncthreads();
        if (tid == 0) {
            float tsum = 0.f;
            #pragma unroll
            for (int w = 0; w < 8; ++w) tsum += red[w];
            atomicAdd(out, tsum);
        }
    }
}

extern "C" void kernel_launch(void* const* d_in, const int* in_sizes, int n_in,
                              void* d_out, int out_size, void* d_ws, size_t ws_size,
                              hipStream_t stream) {
    const float* f1 = (const float*)d_in[0];
    const float* f2 = (const float*)d_in[1];
    const int* label = (const int*)d_in[2];
    float* out = (float*)d_out;

    char* ws = (char*)d_ws;
    unsigned short* featsT = (unsigned short*)ws;                    // 1 MB
    float* NgP    = (float*)(ws + (1u << 20));                       // 2 MB
    float* posdot = (float*)(ws + (3u << 20));                       // 32 KB
    int* cntG     = (int*)(ws + (3u << 20) + 32768);                 // 64 B

    int nb = 0;
    hipOccupancyMaxActiveBlocksPerMultiprocessor(&nb, fused_kernel, 512, 0);
    if (nb < 1) nb = 1;
    int G = nb * 256;                 // 256 CUs on MI355X
    if (G > 1024) G = 1024;
    if (G < 256) G = 256;

    void* args[] = {(void*)&f1, (void*)&f2, (void*)&label, (void*)&featsT,
                    (void*)&posdot, (void*)&NgP, (void*)&cntG, (void*)&out};
    hipLaunchCooperativeKernel(fused_kernel, dim3(G), dim3(512), args, 0, stream);
}

// Round 15
// 84.136 us; speedup vs baseline: 1.8949x; 1.8949x over previous
//
#include <hip/hip_runtime.h>
#include <hip/hip_bf16.h>

#define NROWS 4096
#define TWO_N 8192
#define DDIM 64
#define INV_T 20.0f
// exp(dot*INV_T) = 2^(dot*INV_T*log2e); fold sqrt of the scale into each operand
#define SCALE2 5.3716292f   // sqrt(20 * 1.4426950408889634)
#define CHUNKS 16
#define CPC 512            // columns per chunk
#define JT 8               // 64-col steps per chunk

typedef short bf16x8 __attribute__((ext_vector_type(8)));
typedef float f32x4 __attribute__((ext_vector_type(4)));

__device__ __forceinline__ unsigned short f32_to_bf16_rne(float f) {
    unsigned int u = __float_as_uint(f);
    return (unsigned short)((u + 0x7fffu + ((u >> 16) & 1u)) >> 16);
}

__device__ __forceinline__ float fast_exp2(float x) {
    float r;
    asm("v_exp_f32 %0, %1" : "=v"(r) : "v"(x));
    return r;
}

// featsT fragment-major layout: element (row=16g+lr, col=kb*32+lk*8+e) at
//   featsT[g*1024 + kb*512 + (lk*16+lr)*8 + e]
// -> an MFMA fragment load is featsT + g*1024 + kb*512 + lane*8 (1KB coalesced).

// ---- kernel 1: convert f32 -> scaled bf16 fragment-major + posdot + zero out ----
__global__ void prep_kernel(const float* __restrict__ f1,
                            const float* __restrict__ f2,
                            unsigned short* __restrict__ featsT,
                            float* __restrict__ posdot,
                            float* __restrict__ out) {
    if (blockIdx.x == 0 && threadIdx.x == 0) out[0] = 0.f;
    int t = blockIdx.x * blockDim.x + threadIdx.x;
    int r = t >> 4;
    int q = t & 15;
    int j = r * DDIM + q * 4;
    float4 a = *reinterpret_cast<const float4*>(&f1[j]);
    float4 b = *reinterpret_cast<const float4*>(&f2[j]);
    float d = a.x * b.x + a.y * b.y + a.z * b.z + a.w * b.w;
    d += __shfl_xor(d, 1);
    d += __shfl_xor(d, 2);
    d += __shfl_xor(d, 4);
    d += __shfl_xor(d, 8);
    if (q == 0) posdot[r] = d * INV_T;
    ushort4 ua = make_ushort4(f32_to_bf16_rne(a.x * SCALE2), f32_to_bf16_rne(a.y * SCALE2),
                              f32_to_bf16_rne(a.z * SCALE2), f32_to_bf16_rne(a.w * SCALE2));
    ushort4 ub = make_ushort4(f32_to_bf16_rne(b.x * SCALE2), f32_to_bf16_rne(b.y * SCALE2),
                              f32_to_bf16_rne(b.z * SCALE2), f32_to_bf16_rne(b.w * SCALE2));
    int g1 = r >> 4;
    int lr = r & 15;
    int kb = q >> 3;
    int lk = (q & 7) >> 1;
    int e  = (q & 1) * 4;
    int off = g1 * 1024 + kb * 512 + (lk * 16 + lr) * 8 + e;
    *reinterpret_cast<ushort4*>(&featsT[off]) = ua;                 // f1: groups 0..255
    *reinterpret_cast<ushort4*>(&featsT[off + 256 * 1024]) = ub;    // f2: groups 256..511
}

// ---- kernel 2: NgPart[row][chunk] = sum_{j in chunk, lab_j != lab_i} exp(dot_ij/T) ----
// 1024 blocks (16 chunks x 64 panels), 4 waves/block, 32 rows per wave.
// jt loop software-pipelined with two NAMED B-buffers (bA/bB): tile jt+1's
// 8 fragment loads are in flight while tile jt's MFMA+exp epilogue runs.
// Loop kept rolled (unroll 1); all buffer indices compile-time (no scratch).
__global__ __launch_bounds__(256) void ng_kernel(const unsigned short* __restrict__ featsT,
                                                 const int* __restrict__ label,
                                                 float* __restrict__ NgPart) {
    __shared__ int clabS[CPC];
    __shared__ int rlabS[128];
    const int tid = threadIdx.x;
    const int rowBase = blockIdx.y * 128;
    const int chunk = blockIdx.x;
    const int colBase = chunk * CPC;
    for (int i = tid; i < CPC; i += 256)
        clabS[i] = label[(colBase + i) & (NROWS - 1)];
    if (tid < 128) rlabS[tid] = label[(rowBase + tid) & (NROWS - 1)];
    __syncthreads();

    const int wid = tid >> 6;
    const int lane = tid & 63;
    const int lr = lane & 15;
    const int lk = lane >> 4;
    const int wr = wid * 32;                 // this wave's 32-row slice
    const int gr0 = (rowBase + wr) >> 4;
    const int gc0 = colBase >> 4;

    // A fragments: resident for the whole block
    bf16x8 afr[2][2];
    #pragma unroll
    for (int kb = 0; kb < 2; ++kb)
        #pragma unroll
        for (int m = 0; m < 2; ++m)
            afr[kb][m] = *reinterpret_cast<const bf16x8*>(
                &featsT[(gr0 + m) * 1024 + kb * 512 + lane * 8]);

    int rl[2][4];
    #pragma unroll
    for (int m = 0; m < 2; ++m)
        #pragma unroll
        for (int r = 0; r < 4; ++r)
            rl[m][r] = rlabS[wr + m * 16 + lk * 4 + r];

    float rsum[2][4];
    #pragma unroll
    for (int m = 0; m < 2; ++m)
        #pragma unroll
        for (int r = 0; r < 4; ++r) rsum[m][r] = 0.f;

// load the 8 B fragments (4 col-groups x 2 kb) of tile jt_ into buf
#define LOADB(buf, jt_) do {                                                          \
    int c0_ = gc0 + (jt_) * 4;                                                        \
    _Pragma("unroll")                                                                 \
    for (int n_ = 0; n_ < 4; ++n_) {                                                  \
        buf[n_]     = *reinterpret_cast<const bf16x8*>(                               \
            &featsT[(c0_ + n_) * 1024 +       lane * 8]);                             \
        buf[4 + n_] = *reinterpret_cast<const bf16x8*>(                               \
            &featsT[(c0_ + n_) * 1024 + 512 + lane * 8]);                             \
    }                                                                                 \
} while (0)

// MFMA + masked-exp epilogue for tile jt_ using buf
#define COMPUTE(buf, jt_) do {                                                        \
    f32x4 acc_[2][4];                                                                 \
    f32x4 z_ = {0.f, 0.f, 0.f, 0.f};                                                 \
    _Pragma("unroll")                                                                 \
    for (int m_ = 0; m_ < 2; ++m_)                                                    \
        _Pragma("unroll")                                                             \
        for (int n_ = 0; n_ < 4; ++n_) acc_[m_][n_] = z_;                             \
    _Pragma("unroll")                                                                 \
    for (int m_ = 0; m_ < 2; ++m_)                                                    \
        _Pragma("unroll")                                                             \
        for (int n_ = 0; n_ < 4; ++n_)                                                \
            acc_[m_][n_] = __builtin_amdgcn_mfma_f32_16x16x32_bf16(                   \
                afr[0][m_], buf[n_], acc_[m_][n_], 0, 0, 0);                          \
    _Pragma("unroll")                                                                 \
    for (int m_ = 0; m_ < 2; ++m_)                                                    \
        _Pragma("unroll")                                                             \
        for (int n_ = 0; n_ < 4; ++n_)                                                \
            acc_[m_][n_] = __builtin_amdgcn_mfma_f32_16x16x32_bf16(                   \
                afr[1][m_], buf[4 + n_], acc_[m_][n_], 0, 0, 0);                      \
    int cl_[4];                                                                       \
    _Pragma("unroll")                                                                 \
    for (int n_ = 0; n_ < 4; ++n_) cl_[n_] = clabS[(jt_) * 64 + n_ * 16 + lr];        \
    _Pragma("unroll")                                                                 \
    for (int m_ = 0; m_ < 2; ++m_)                                                    \
        _Pragma("unroll")                                                             \
        for (int r_ = 0; r_ < 4; ++r_) {                                              \
            int lab_ = rl[m_][r_];                                                    \
            float s_ = 0.f;                                                           \
            _Pragma("unroll")                                                         \
            for (int n_ = 0; n_ < 4; ++n_) {                                          \
                float e_ = fast_exp2(acc_[m_][n_][r_]);                               \
                s_ += (cl_[n_] != lab_) ? e_ : 0.f;                                   \
            }                                                                         \
            rsum[m_][r_] += s_;                                                       \
        }                                                                             \
} while (0)

    bf16x8 bA[8], bB[8];
    LOADB(bA, 0);
    #pragma unroll 1
    for (int jt = 0; jt < JT; jt += 2) {
        LOADB(bB, jt + 1);          // in flight during COMPUTE(bA)
        COMPUTE(bA, jt);
        if (jt + 2 < JT) LOADB(bA, jt + 2);   // in flight during COMPUTE(bB)
        COMPUTE(bB, jt + 1);
    }
#undef LOADB
#undef COMPUTE

    // reduce across the 16 lr lanes; plain store (no atomics)
    #pragma unroll
    for (int m = 0; m < 2; ++m)
        #pragma unroll
        for (int r = 0; r < 4; ++r) {
            float v = rsum[m][r];
            v += __shfl_xor(v, 1);
            v += __shfl_xor(v, 2);
            v += __shfl_xor(v, 4);
            v += __shfl_xor(v, 8);
            if (lr == 0)
                NgPart[(size_t)(rowBase + wr + m * 16 + lk * 4 + r) * CHUNKS + chunk] = v;
        }
}

// ---- kernel 3: final loss (32 blocks x 256 threads) ----
__global__ void final_kernel(const float* __restrict__ NgPart,
                             const float* __restrict__ posdot,
                             const int* __restrict__ label,
                             float* __restrict__ out) {
    __shared__ int cnt[16];
    __shared__ float red[4];
    int tid = threadIdx.x;
    if (tid < 16) cnt[tid] = 0;
    __syncthreads();
    for (int i = tid; i < NROWS; i += 256) atomicAdd(&cnt[label[i]], 1);
    __syncthreads();

    int i = blockIdx.x * 256 + tid;
    float ng = 0.f;
    #pragma unroll
    for (int c = 0; c < CHUNKS / 4; ++c) {
        float4 p = *reinterpret_cast<const float4*>(&NgPart[(size_t)i * CHUNKS + c * 4]);
        ng += (p.x + p.y) + (p.z + p.w);
    }
    int base = i & (NROWS - 1);
    float pd = posdot[base];
    float gs = 2.0f * (float)cnt[label[base]];
    float s = (__logf(ng + __expf(pd)) - pd) / gs;

    #pragma unroll
    for (int m = 32; m; m >>= 1) s += __shfl_xor(s, m);
    if ((tid & 63) == 0) red[tid >> 6] = s;
    __syncthreads();
    if (tid == 0) atomicAdd(out, red[0] + red[1] + red[2] + red[3]);
}

extern "C" void kernel_launch(void* const* d_in, const int* in_sizes, int n_in,
                              void* d_out, int out_size, void* d_ws, size_t ws_size,
                              hipStream_t stream) {
    const float* f1 = (const float*)d_in[0];
    const float* f2 = (const float*)d_in[1];
    const int* label = (const int*)d_in[2];
    float* out = (float*)d_out;

    char* ws = (char*)d_ws;
    unsigned short* featsT = (unsigned short*)ws;                    // 1 MB
    float* NgPart = (float*)(ws + (1u << 20));                       // 512 KB
    float* posdot = (float*)(ws + (1u << 20) + (TWO_N * CHUNKS * 4));// 32 KB

    prep_kernel<<<dim3(NROWS * DDIM / 4 / 256), dim3(256), 0, stream>>>(f1, f2, featsT, posdot, out);
    ng_kernel<<<dim3(CHUNKS, TWO_N / 128), dim3(256), 0, stream>>>(featsT, label, NgPart);
    final_kernel<<<dim3(TWO_N / 256), dim3(256), 0, stream>>>(NgPart, posdot, label, out);
}